// Round 6
// baseline (444.130 us; speedup 1.0000x reference)
//
#include <hip/hip_runtime.h>
#include <hip/hip_bf16.h>

#define BB 4
#define CC 256
#define NN 4096
#define SS 3
#define C8 32
#define L2E 1.4426950408889634f

typedef __attribute__((ext_vector_type(8))) short short8;
typedef __attribute__((ext_vector_type(4))) float floatx4;

static __device__ inline unsigned pack_bf16(float a, float b) {
  union { __hip_bfloat16 h; unsigned short u; } ua, ub;
  ua.h = __float2bfloat16(a);
  ub.h = __float2bfloat16(b);
  return ((unsigned)ub.u << 16) | (unsigned)ua.u;
}

static __device__ inline float fast_exp2(float x) {
#if __has_builtin(__builtin_amdgcn_exp2f)
  return __builtin_amdgcn_exp2f(x);
#else
  return exp2f(x);
#endif
}

// ---------------------------------------------------------------------------
// T1: input transposes + weight convert, merged.
// z<12: xbT[z] <- x_b[z]; z<16: xfT[z-12] <- x_f; z==16: weight fp32->bf16.
// ---------------------------------------------------------------------------
__global__ void __launch_bounds__(256) transpose_in_kernel(
    const float* __restrict__ xb, const float* __restrict__ xf,
    __hip_bfloat16* __restrict__ xbT, __hip_bfloat16* __restrict__ xfT,
    const float* __restrict__ Wq, const float* __restrict__ Wk,
    const float* __restrict__ Wv, const float* __restrict__ Wf,
    __hip_bfloat16* __restrict__ WqB, __hip_bfloat16* __restrict__ WkB,
    __hip_bfloat16* __restrict__ WvB, __hip_bfloat16* __restrict__ WfB) {
  __shared__ float ts[64][65];
  const int z = blockIdx.z;
  const int t = threadIdx.x;
  if (z == 16) {  // weight conversion plane: 256 blocks x 256 thr, 4 strides
    for (int idx = (blockIdx.y * 64 + blockIdx.x) * 256 + t; idx < 212992;
         idx += 65536) {
      if (idx < 8192) WqB[idx] = __float2bfloat16(Wq[idx] * L2E);
      else if (idx < 16384) WkB[idx - 8192] = __float2bfloat16(Wk[idx - 8192]);
      else if (idx < 81920) WvB[idx - 16384] = __float2bfloat16(Wv[idx - 16384]);
      else WfB[idx - 81920] = __float2bfloat16(Wf[idx - 81920]);
    }
    return;
  }
  const bool isb = (z < 12);
  const int g = isb ? z : z - 12;
  const float* X = (isb ? xb : xf) + (size_t)g * CC * NN;
  __hip_bfloat16* out = (isb ? xbT : xfT) + (size_t)g * NN * CC;
  const int c0 = blockIdx.y * 64, n0 = blockIdx.x * 64;
  const float* Xg = X + (size_t)c0 * NN + n0;
  for (int idx = t; idx < 64 * 64; idx += 256) {
    int r = idx >> 6, qq = idx & 63;
    ts[r][qq] = Xg[(size_t)r * NN + qq];
  }
  __syncthreads();
  __hip_bfloat16* og = out + (size_t)n0 * CC + c0;
  for (int idx = t; idx < 64 * 32; idx += 256) {
    int n = idx >> 5, pc = idx & 31;
    ((unsigned*)(og + (size_t)n * CC))[pc] = pack_bf16(ts[2 * pc][n], ts[2 * pc + 1][n]);
  }
}

// ---------------------------------------------------------------------------
// G1+G2 merged: y<12 -> v projection for g=y; y>=12 -> q/k projection.
// ---------------------------------------------------------------------------
__global__ void __launch_bounds__(256) projqkv_kernel(
    const __hip_bfloat16* __restrict__ xbT, const __hip_bfloat16* __restrict__ xfT,
    const __hip_bfloat16* __restrict__ WqB, const __hip_bfloat16* __restrict__ WkB,
    const __hip_bfloat16* __restrict__ WvB,
    const float* __restrict__ bq, const float* __restrict__ bk,
    const float* __restrict__ bv,
    __hip_bfloat16* __restrict__ qT, __hip_bfloat16* __restrict__ kT,
    __hip_bfloat16* __restrict__ vB) {
  const int y = blockIdx.y;
  const int t = threadIdx.x, w = t >> 6, lane = t & 63;
  const int q = lane >> 4, li = lane & 15;
  floatx4 zf = {0.f, 0.f, 0.f, 0.f};
  if (y < 12) {  // ---- v projection: vB[g][o][n] = Wv @ xbT[g] + bv ----
    const int g = y, n0 = blockIdx.x * 64;
    const __hip_bfloat16* src = xbT + (size_t)g * NN * CC;
    __hip_bfloat16* dst = vB + (size_t)g * CC * NN;
    const int o_w = w * 64;
    floatx4 acc[4][4];
#pragma unroll
    for (int ot = 0; ot < 4; ++ot)
#pragma unroll
      for (int nt = 0; nt < 4; ++nt) acc[ot][nt] = zf;
#pragma unroll
    for (int kc = 0; kc < 8; ++kc) {
      short8 a[4], bfr[4];
#pragma unroll
      for (int ot = 0; ot < 4; ++ot)
        a[ot] = *(const short8*)(WvB + (size_t)(o_w + ot * 16 + li) * CC + kc * 32 + q * 8);
#pragma unroll
      for (int nt = 0; nt < 4; ++nt)
        bfr[nt] = *(const short8*)(src + (size_t)(n0 + nt * 16 + li) * CC + kc * 32 + q * 8);
#pragma unroll
      for (int ot = 0; ot < 4; ++ot)
#pragma unroll
        for (int nt = 0; nt < 4; ++nt)
          acc[ot][nt] = __builtin_amdgcn_mfma_f32_16x16x32_bf16(a[ot], bfr[nt],
                                                                acc[ot][nt], 0, 0, 0);
    }
#pragma unroll
    for (int ot = 0; ot < 4; ++ot) {
#pragma unroll
      for (int r = 0; r < 4; ++r) {
        int o = o_w + ot * 16 + q * 4 + r;
        float bo = bv[o];
#pragma unroll
        for (int nt = 0; nt < 4; ++nt)
          dst[(size_t)o * NN + n0 + nt * 16 + li] =
              __float2bfloat16(acc[ot][nt][r] + bo);
      }
    }
  } else {  // ---- q/k projection, n-tile 64 (16/wave) ----
    const int gg = y - 12;
    const bool qm = (gg < 12);
    const int g = qm ? gg : gg - 12;
    const __hip_bfloat16* src = (qm ? xbT : xfT) + (size_t)g * NN * CC;
    const __hip_bfloat16* W = qm ? WqB : WkB;
    const float* bias = qm ? bq : bk;
    const float bscale = qm ? L2E : 1.f;
    __hip_bfloat16* dst = (qm ? qT : kT) + (size_t)g * NN * C8;
    const int n_w = blockIdx.x * 64 + w * 16;
    floatx4 acc[2];
    acc[0] = zf; acc[1] = zf;
#pragma unroll
    for (int kc = 0; kc < 8; ++kc) {
      short8 a[2];
#pragma unroll
      for (int ot = 0; ot < 2; ++ot)
        a[ot] = *(const short8*)(W + (size_t)(ot * 16 + li) * CC + kc * 32 + q * 8);
      short8 bfr = *(const short8*)(src + (size_t)(n_w + li) * CC + kc * 32 + q * 8);
#pragma unroll
      for (int ot = 0; ot < 2; ++ot)
        acc[ot] = __builtin_amdgcn_mfma_f32_16x16x32_bf16(a[ot], bfr, acc[ot], 0, 0, 0);
    }
#pragma unroll
    for (int ot = 0; ot < 2; ++ot) {
      float bv0 = bias[ot * 16 + q * 4 + 0] * bscale;
      float bv1 = bias[ot * 16 + q * 4 + 1] * bscale;
      float bv2 = bias[ot * 16 + q * 4 + 2] * bscale;
      float bv3 = bias[ot * 16 + q * 4 + 3] * bscale;
      int n = n_w + li;
      uint2 pk;
      pk.x = pack_bf16(acc[ot][0] + bv0, acc[ot][1] + bv1);
      pk.y = pack_bf16(acc[ot][2] + bv2, acc[ot][3] + bv3);
      *(uint2*)(dst + (size_t)n * C8 + ot * 16 + q * 4) = pk;
    }
  }
}

// ---------------------------------------------------------------------------
// K3: BARRIER-FREE MFMA flash attention. Each wave independently owns
// (g, i-strip 64, c-quarter 64) and iterates ALL j. The QK^T A-fragment is
// loaded with the permuted row map j = jb + 8*(li>>2) + (li&3) (second frag
// +4), so the MFMA C-layout (col=li, row=4q+r) lands S^T values exactly at
// the lanes/slots the PV B-operand needs (k = q*8+e -> j = jb+8q+e):
// pf = {pack(e1_0,e1_1),pack(e1_2,e1_3),pack(e2_0,e2_1),pack(e2_2,e2_3)}.
// P never leaves the lane: no LDS, no barrier, no shuffles, no atomics.
// Cost: QK/exp recomputed per c-wave (4x) — traded for zero sync stalls.
// 4 waves/block share (g,i0): identical qf/kf loads (L1), disjoint c.
// Regs: acc 64 AGPR + ~105 arch -> ~3 waves/SIMD.
// ---------------------------------------------------------------------------
__global__ void __launch_bounds__(256) attn_kernel(
    const __hip_bfloat16* __restrict__ qT, const __hip_bfloat16* __restrict__ kT,
    const __hip_bfloat16* __restrict__ vB, float* __restrict__ outs_s) {
  const int x_ = blockIdx.x;
  const int wk = (x_ & 7) * 96 + (x_ >> 3);  // contiguous range per XCD
  const int g  = wk >> 6;                    // 0..11 (= s*4+b)
  const int u  = wk & 63;
  const int b  = g & 3;
  const int t  = threadIdx.x;
  const int w  = t >> 6;
  const int lane = t & 63, q = lane >> 4, li = lane & 15;
  const int i0 = u * 64;        // i-strip of this block (all 4 waves)
  const int c0 = w * 64;        // c-quarter of this wave

  floatx4 zf = {0.f, 0.f, 0.f, 0.f};
  short8 qf[4];
#pragma unroll
  for (int it = 0; it < 4; ++it)
    qf[it] = *(const short8*)(qT + ((size_t)g * NN + i0 + it * 16 + li) * C8 + q * 8);

  floatx4 acc[4][4];
#pragma unroll
  for (int ct = 0; ct < 4; ++ct)
#pragma unroll
    for (int it = 0; it < 4; ++it) acc[ct][it] = zf;
  float rsum[4] = {0.f, 0.f, 0.f, 0.f};

  const __hip_bfloat16* kb = kT + (size_t)b * NN * C8;
  const __hip_bfloat16* vb = vB + (size_t)g * CC * NN;
  // permuted K row offset: A-row a=li holds K row jb + 8*(li>>2)+(li&3)
  const int kroff = 8 * (li >> 2) + (li & 3);
  short8 kf0 = *(const short8*)(kb + (size_t)(kroff) * C8 + q * 8);
  short8 kf1 = *(const short8*)(kb + (size_t)(kroff + 4) * C8 + q * 8);

  for (int jb = 0; jb < NN; jb += 32) {
    // V frags for this step: issued first, consumed after the QK/exp phase
    short8 vf[4];
#pragma unroll
    for (int ct = 0; ct < 4; ++ct)
      vf[ct] = *(const short8*)(vb + (size_t)(c0 + ct * 16 + li) * NN + jb + q * 8);
    // prefetch next step's K frags (wrap harmless)
    int jn = (jb + 32) & (NN - 1);
    short8 kf0n = *(const short8*)(kb + (size_t)(jn + kroff) * C8 + q * 8);
    short8 kf1n = *(const short8*)(kb + (size_t)(jn + kroff + 4) * C8 + q * 8);
    // QK^T -> exp2 -> pack, fully in-lane
    short8 pf[4];
#pragma unroll
    for (int it = 0; it < 4; ++it) {
      floatx4 s1 = __builtin_amdgcn_mfma_f32_16x16x32_bf16(kf0, qf[it], zf, 0, 0, 0);
      floatx4 s2 = __builtin_amdgcn_mfma_f32_16x16x32_bf16(kf1, qf[it], zf, 0, 0, 0);
      float e0 = fast_exp2(s1[0]), e1 = fast_exp2(s1[1]);
      float e2 = fast_exp2(s1[2]), e3 = fast_exp2(s1[3]);
      float f0 = fast_exp2(s2[0]), f1 = fast_exp2(s2[1]);
      float f2 = fast_exp2(s2[2]), f3 = fast_exp2(s2[3]);
      rsum[it] += ((e0 + e1) + (e2 + e3)) + ((f0 + f1) + (f2 + f3));
      unsigned pu[4];
      pu[0] = pack_bf16(e0, e1);
      pu[1] = pack_bf16(e2, e3);
      pu[2] = pack_bf16(f0, f1);
      pu[3] = pack_bf16(f2, f3);
      pf[it] = *(const short8*)pu;
    }
    // PV accumulate
#pragma unroll
    for (int ct = 0; ct < 4; ++ct)
#pragma unroll
      for (int it = 0; it < 4; ++it)
        acc[ct][it] = __builtin_amdgcn_mfma_f32_16x16x32_bf16(
            vf[ct], pf[it], acc[ct][it], 0, 0, 0);
    kf0 = kf0n;
    kf1 = kf1n;
  }
  // row-sum: each lane holds partials for j = 8q+{0..7} (mod 32); reduce
  // across the quadrant bits (lanes ^16, ^32) -> full sum per i-col (li).
  float inv[4];
#pragma unroll
  for (int it = 0; it < 4; ++it) {
    float v = rsum[it];
    v += __shfl_xor(v, 16, 64);
    v += __shfl_xor(v, 32, 64);
    inv[it] = 1.0f / v;
  }
  float* ob = outs_s + (size_t)g * CC * NN + i0;
#pragma unroll
  for (int ct = 0; ct < 4; ++ct)
#pragma unroll
    for (int it = 0; it < 4; ++it)
#pragma unroll
      for (int r = 0; r < 4; ++r) {
        int c = c0 + ct * 16 + q * 4 + r;
        ob[(size_t)c * NN + it * 16 + li] = acc[ct][it][r] * inv[it];
      }
}

// ---------------------------------------------------------------------------
// G3: final projection with T2 fused (3-way s-sum + gamma + transpose staged
// through LDS), n-tile 32, grid (128, 4).
// ---------------------------------------------------------------------------
__global__ void __launch_bounds__(256) final_kernel(
    const float* __restrict__ outs_s, const __hip_bfloat16* __restrict__ xfT,
    const __hip_bfloat16* __restrict__ WfB, const float* __restrict__ bfv,
    const float* __restrict__ gp, float* __restrict__ out) {
  __shared__ float ts[64][33];
  __shared__ __hip_bfloat16 Pn[32][280];
  const int b = blockIdx.y, n0 = blockIdx.x * 32;
  const int t = threadIdx.x, w = t >> 6, lane = t & 63;
  const int q = lane >> 4, li = lane & 15;
  const float sc = gp[0];
  for (int cc = 0; cc < 4; ++cc) {
    const int c0 = cc * 64;
    const float* X0 = outs_s + ((size_t)(0 + b) * CC + c0) * NN + n0;
    const float* X1 = outs_s + ((size_t)(4 + b) * CC + c0) * NN + n0;
    const float* X2 = outs_s + ((size_t)(8 + b) * CC + c0) * NN + n0;
    for (int idx = t; idx < 64 * 32; idx += 256) {
      int r = idx >> 5, col = idx & 31;
      size_t off = (size_t)r * NN + col;
      ts[r][col] = X0[off] + X1[off] + X2[off];
    }
    __syncthreads();
    for (int idx = t; idx < 32 * 32; idx += 256) {
      int n = idx >> 5, pc = idx & 31;
      ((unsigned*)&Pn[n][c0])[pc] =
          pack_bf16(ts[2 * pc][n] * sc, ts[2 * pc + 1][n] * sc);
    }
    __syncthreads();
  }
  const __hip_bfloat16* xT = xfT + (size_t)b * NN * CC;
  const int o_w = w * 64;
  floatx4 acc[4][2];
  floatx4 zf = {0.f, 0.f, 0.f, 0.f};
#pragma unroll
  for (int ot = 0; ot < 4; ++ot)
#pragma unroll
    for (int nt = 0; nt < 2; ++nt) acc[ot][nt] = zf;
#pragma unroll
  for (int kc = 0; kc < 16; ++kc) {
    short8 a[4], bfr[2];
#pragma unroll
    for (int ot = 0; ot < 4; ++ot)
      a[ot] = *(const short8*)(WfB + (size_t)(o_w + ot * 16 + li) * (2 * CC) +
                               kc * 32 + q * 8);
    if (kc < 8) {
#pragma unroll
      for (int nt = 0; nt < 2; ++nt)
        bfr[nt] = *(const short8*)(&Pn[nt * 16 + li][kc * 32 + q * 8]);
    } else {
#pragma unroll
      for (int nt = 0; nt < 2; ++nt)
        bfr[nt] = *(const short8*)(xT + (size_t)(n0 + nt * 16 + li) * CC +
                                   (kc - 8) * 32 + q * 8);
    }
#pragma unroll
    for (int ot = 0; ot < 4; ++ot)
#pragma unroll
      for (int nt = 0; nt < 2; ++nt)
        acc[ot][nt] = __builtin_amdgcn_mfma_f32_16x16x32_bf16(a[ot], bfr[nt],
                                                              acc[ot][nt], 0, 0, 0);
  }
  float* ob = out + (size_t)b * CC * NN;
#pragma unroll
  for (int ot = 0; ot < 4; ++ot)
#pragma unroll
    for (int r = 0; r < 4; ++r) {
      int o = o_w + ot * 16 + q * 4 + r;
      float bo = bfv[o];
#pragma unroll
      for (int nt = 0; nt < 2; ++nt)
        ob[(size_t)o * NN + n0 + nt * 16 + li] = acc[ot][nt][r] + bo;
    }
}

// ---------------------------------------------------------------------------
extern "C" void kernel_launch(void* const* d_in, const int* in_sizes, int n_in,
                              void* d_out, int out_size, void* d_ws,
                              size_t ws_size, hipStream_t stream) {
  const float* x_f = (const float*)d_in[0];
  const float* x_b = (const float*)d_in[1];
  const float* Wq  = (const float*)d_in[2];
  const float* bq  = (const float*)d_in[3];
  const float* Wk  = (const float*)d_in[4];
  const float* bk  = (const float*)d_in[5];
  const float* Wv  = (const float*)d_in[6];
  const float* bv  = (const float*)d_in[7];
  const float* Wf  = (const float*)d_in[8];
  const float* bf  = (const float*)d_in[9];
  const float* gm  = (const float*)d_in[10];
  float* out = (float*)d_out;

  // workspace layout — peak 84.4 MB via aliasing:
  //   [ 0..24) vB       bf16 [12][256][4096]   (projqkv -> attn)
  //   [24..32) xfT      bf16 [4][4096][256]    (transpose -> final)
  //   [32..80) outs_s   f32  [12][256][4096]   (attn -> final)
  //            xbT      bf16 [12][4096][256]   (transpose -> projqkv) ALIAS
  //   [80..83) qT, [83..84) kT, [84..84.41) weights
  char* ws = (char*)d_ws;
  __hip_bfloat16* vB     = (__hip_bfloat16*)ws;                         // 24 MB
  __hip_bfloat16* xfT    = (__hip_bfloat16*)(ws + ((size_t)24 << 20));  //  8 MB
  float*          outs_s = (float*)(ws + ((size_t)32 << 20));           // 48 MB
  __hip_bfloat16* xbT    = (__hip_bfloat16*)(ws + ((size_t)32 << 20));  // 24 MB (alias outs_s)
  __hip_bfloat16* qT     = (__hip_bfloat16*)(ws + ((size_t)80 << 20));  //  3 MB
  __hip_bfloat16* kT     = (__hip_bfloat16*)(ws + ((size_t)83 << 20));  //  1 MB
  __hip_bfloat16* WqB    = (__hip_bfloat16*)(ws + ((size_t)84 << 20));  // 16 KB
  __hip_bfloat16* WkB    = WqB + 8192;                                  // 16 KB
  __hip_bfloat16* WvB    = WkB + 8192;                                  // 128 KB
  __hip_bfloat16* WfB    = WvB + 65536;                                 // 256 KB

  hipLaunchKernelGGL(transpose_in_kernel, dim3(NN / 64, CC / 64, 17),
                     dim3(256), 0, stream, x_b, x_f, xbT, xfT,
                     Wq, Wk, Wv, Wf, WqB, WkB, WvB, WfB);
  hipLaunchKernelGGL(projqkv_kernel, dim3(NN / 64, 28), dim3(256), 0, stream,
                     xbT, xfT, WqB, WkB, WvB, bq, bk, bv, qT, kT, vB);
  hipLaunchKernelGGL(attn_kernel, dim3(768), dim3(256), 0, stream,
                     qT, kT, vB, outs_s);
  hipLaunchKernelGGL(final_kernel, dim3(NN / 32, BB), dim3(256), 0, stream,
                     outs_s, xfT, WfB, bf, gm, out);
}

// Round 8
// 439.560 us; speedup vs baseline: 1.0104x; 1.0104x over previous
//
#include <hip/hip_runtime.h>
#include <hip/hip_bf16.h>

#define BB 4
#define CC 256
#define NN 4096
#define SS 3
#define C8 32
#define L2E 1.4426950408889634f

typedef __attribute__((ext_vector_type(8))) short short8;
typedef __attribute__((ext_vector_type(4))) float floatx4;
typedef __attribute__((ext_vector_type(4))) unsigned uintx4;

static __device__ inline unsigned pack_bf16(float a, float b) {
  union { __hip_bfloat16 h; unsigned short u; } ua, ub;
  ua.h = __float2bfloat16(a);
  ub.h = __float2bfloat16(b);
  return ((unsigned)ub.u << 16) | (unsigned)ua.u;
}

// hardware packed convert: one v_cvt_pk_bf16_f32 (RNE) per pair
static __device__ inline unsigned cvt_pk_bf16(float a, float b) {
  union { __hip_bfloat162 h2; unsigned u; } cv;
  cv.h2 = __float22bfloat162_rn(make_float2(a, b));
  return cv.u;
}

static __device__ inline float fast_exp2(float x) {
#if __has_builtin(__builtin_amdgcn_exp2f)
  return __builtin_amdgcn_exp2f(x);
#else
  return exp2f(x);
#endif
}

// ---------------------------------------------------------------------------
// T1: input transposes + weight convert, merged.
// z<12: xbT[z] <- x_b[z]; z<16: xfT[z-12] <- x_f; z==16: weight fp32->bf16.
// ---------------------------------------------------------------------------
__global__ void __launch_bounds__(256) transpose_in_kernel(
    const float* __restrict__ xb, const float* __restrict__ xf,
    __hip_bfloat16* __restrict__ xbT, __hip_bfloat16* __restrict__ xfT,
    const float* __restrict__ Wq, const float* __restrict__ Wk,
    const float* __restrict__ Wv, const float* __restrict__ Wf,
    __hip_bfloat16* __restrict__ WqB, __hip_bfloat16* __restrict__ WkB,
    __hip_bfloat16* __restrict__ WvB, __hip_bfloat16* __restrict__ WfB) {
  __shared__ float ts[64][65];
  const int z = blockIdx.z;
  const int t = threadIdx.x;
  if (z == 16) {  // weight conversion plane: 256 blocks x 256 thr, 4 strides
    for (int idx = (blockIdx.y * 64 + blockIdx.x) * 256 + t; idx < 212992;
         idx += 65536) {
      if (idx < 8192) WqB[idx] = __float2bfloat16(Wq[idx] * L2E);
      else if (idx < 16384) WkB[idx - 8192] = __float2bfloat16(Wk[idx - 8192]);
      else if (idx < 81920) WvB[idx - 16384] = __float2bfloat16(Wv[idx - 16384]);
      else WfB[idx - 81920] = __float2bfloat16(Wf[idx - 81920]);
    }
    return;
  }
  const bool isb = (z < 12);
  const int g = isb ? z : z - 12;
  const float* X = (isb ? xb : xf) + (size_t)g * CC * NN;
  __hip_bfloat16* out = (isb ? xbT : xfT) + (size_t)g * NN * CC;
  const int c0 = blockIdx.y * 64, n0 = blockIdx.x * 64;
  const float* Xg = X + (size_t)c0 * NN + n0;
  for (int idx = t; idx < 64 * 64; idx += 256) {
    int r = idx >> 6, qq = idx & 63;
    ts[r][qq] = Xg[(size_t)r * NN + qq];
  }
  __syncthreads();
  __hip_bfloat16* og = out + (size_t)n0 * CC + c0;
  for (int idx = t; idx < 64 * 32; idx += 256) {
    int n = idx >> 5, pc = idx & 31;
    ((unsigned*)(og + (size_t)n * CC))[pc] = pack_bf16(ts[2 * pc][n], ts[2 * pc + 1][n]);
  }
}

// ---------------------------------------------------------------------------
// G1+G2 merged: y<12 -> v projection for g=y; y>=12 -> q/k projection.
// ---------------------------------------------------------------------------
__global__ void __launch_bounds__(256) projqkv_kernel(
    const __hip_bfloat16* __restrict__ xbT, const __hip_bfloat16* __restrict__ xfT,
    const __hip_bfloat16* __restrict__ WqB, const __hip_bfloat16* __restrict__ WkB,
    const __hip_bfloat16* __restrict__ WvB,
    const float* __restrict__ bq, const float* __restrict__ bk,
    const float* __restrict__ bv,
    __hip_bfloat16* __restrict__ qT, __hip_bfloat16* __restrict__ kT,
    __hip_bfloat16* __restrict__ vB) {
  const int y = blockIdx.y;
  const int t = threadIdx.x, w = t >> 6, lane = t & 63;
  const int q = lane >> 4, li = lane & 15;
  floatx4 zf = {0.f, 0.f, 0.f, 0.f};
  if (y < 12) {  // ---- v projection: vB[g][o][n] = Wv @ xbT[g] + bv ----
    const int g = y, n0 = blockIdx.x * 64;
    const __hip_bfloat16* src = xbT + (size_t)g * NN * CC;
    __hip_bfloat16* dst = vB + (size_t)g * CC * NN;
    const int o_w = w * 64;
    floatx4 acc[4][4];
#pragma unroll
    for (int ot = 0; ot < 4; ++ot)
#pragma unroll
      for (int nt = 0; nt < 4; ++nt) acc[ot][nt] = zf;
#pragma unroll
    for (int kc = 0; kc < 8; ++kc) {
      short8 a[4], bfr[4];
#pragma unroll
      for (int ot = 0; ot < 4; ++ot)
        a[ot] = *(const short8*)(WvB + (size_t)(o_w + ot * 16 + li) * CC + kc * 32 + q * 8);
#pragma unroll
      for (int nt = 0; nt < 4; ++nt)
        bfr[nt] = *(const short8*)(src + (size_t)(n0 + nt * 16 + li) * CC + kc * 32 + q * 8);
#pragma unroll
      for (int ot = 0; ot < 4; ++ot)
#pragma unroll
        for (int nt = 0; nt < 4; ++nt)
          acc[ot][nt] = __builtin_amdgcn_mfma_f32_16x16x32_bf16(a[ot], bfr[nt],
                                                                acc[ot][nt], 0, 0, 0);
    }
#pragma unroll
    for (int ot = 0; ot < 4; ++ot) {
#pragma unroll
      for (int r = 0; r < 4; ++r) {
        int o = o_w + ot * 16 + q * 4 + r;
        float bo = bv[o];
#pragma unroll
        for (int nt = 0; nt < 4; ++nt)
          dst[(size_t)o * NN + n0 + nt * 16 + li] =
              __float2bfloat16(acc[ot][nt][r] + bo);
      }
    }
  } else {  // ---- q/k projection, n-tile 64 (16/wave) ----
    const int gg = y - 12;
    const bool qm = (gg < 12);
    const int g = qm ? gg : gg - 12;
    const __hip_bfloat16* src = (qm ? xbT : xfT) + (size_t)g * NN * CC;
    const __hip_bfloat16* W = qm ? WqB : WkB;
    const float* bias = qm ? bq : bk;
    const float bscale = qm ? L2E : 1.f;
    __hip_bfloat16* dst = (qm ? qT : kT) + (size_t)g * NN * C8;
    const int n_w = blockIdx.x * 64 + w * 16;
    floatx4 acc[2];
    acc[0] = zf; acc[1] = zf;
#pragma unroll
    for (int kc = 0; kc < 8; ++kc) {
      short8 a[2];
#pragma unroll
      for (int ot = 0; ot < 2; ++ot)
        a[ot] = *(const short8*)(W + (size_t)(ot * 16 + li) * CC + kc * 32 + q * 8);
      short8 bfr = *(const short8*)(src + (size_t)(n_w + li) * CC + kc * 32 + q * 8);
#pragma unroll
      for (int ot = 0; ot < 2; ++ot)
        acc[ot] = __builtin_amdgcn_mfma_f32_16x16x32_bf16(a[ot], bfr, acc[ot], 0, 0, 0);
    }
#pragma unroll
    for (int ot = 0; ot < 2; ++ot) {
      float bv0 = bias[ot * 16 + q * 4 + 0] * bscale;
      float bv1 = bias[ot * 16 + q * 4 + 1] * bscale;
      float bv2 = bias[ot * 16 + q * 4 + 2] * bscale;
      float bv3 = bias[ot * 16 + q * 4 + 3] * bscale;
      int n = n_w + li;
      uint2 pk;
      pk.x = pack_bf16(acc[ot][0] + bv0, acc[ot][1] + bv1);
      pk.y = pack_bf16(acc[ot][2] + bv2, acc[ot][3] + bv3);
      *(uint2*)(dst + (size_t)n * C8 + ot * 16 + q * 4) = pk;
    }
  }
}

// ---------------------------------------------------------------------------
// K3: BARRIER-FREE MFMA flash attention, VALU-dieted (round-7 retry; the
// only change vs round 7 is the union-based cvt_pk_bf16 — bit_cast rejected
// __hip_bfloat162 as non-trivially-copyable).
//  (1) v_cvt_pk_bf16_f32 via __float22bfloat162_rn,
//  (2) softmax denom via ones-MFMA (zero VALU adds / end-shuffles),
//  (3) vfa/vfb V double-buffer + hoisted row bases.
// ---------------------------------------------------------------------------
__global__ void __launch_bounds__(256) attn_kernel(
    const __hip_bfloat16* __restrict__ qT, const __hip_bfloat16* __restrict__ kT,
    const __hip_bfloat16* __restrict__ vB, float* __restrict__ outs_s) {
  const int x_ = blockIdx.x;
  const int wk = (x_ & 7) * 96 + (x_ >> 3);  // contiguous range per XCD
  const int g  = wk >> 6;                    // 0..11 (= s*4+b)
  const int u  = wk & 63;
  const int b  = g & 3;
  const int t  = threadIdx.x;
  const int w  = t >> 6;
  const int lane = t & 63, q = lane >> 4, li = lane & 15;
  const int i0 = u * 64;        // i-strip of this block (all 4 waves)
  const int c0 = w * 64;        // c-quarter of this wave

  floatx4 zf = {0.f, 0.f, 0.f, 0.f};
  const short ONE = (short)0x3F80;  // bf16 1.0
  const short8 ones = {ONE, ONE, ONE, ONE, ONE, ONE, ONE, ONE};

  short8 qf[4];
#pragma unroll
  for (int it = 0; it < 4; ++it)
    qf[it] = *(const short8*)(qT + ((size_t)g * NN + i0 + it * 16 + li) * C8 + q * 8);

  floatx4 acc[4][4];
#pragma unroll
  for (int ct = 0; ct < 4; ++ct)
#pragma unroll
    for (int it = 0; it < 4; ++it) acc[ct][it] = zf;
  floatx4 rsacc[4];
#pragma unroll
  for (int it = 0; it < 4; ++it) rsacc[it] = zf;

  const __hip_bfloat16* kb = kT + (size_t)b * NN * C8;
  const __hip_bfloat16* vb = vB + (size_t)g * CC * NN;
  // permuted K row offset: A-row a=li holds K row jb + 8*(li>>2)+(li&3)
  const int kroff = 8 * (li >> 2) + (li & 3);
  const __hip_bfloat16* krow = kb + (size_t)kroff * C8 + q * 8;  // + j*C8
  const __hip_bfloat16* vrow[4];
#pragma unroll
  for (int ct = 0; ct < 4; ++ct)
    vrow[ct] = vb + (size_t)(c0 + ct * 16 + li) * NN + q * 8;    // + j

  short8 kf0 = *(const short8*)(krow);
  short8 kf1 = *(const short8*)(krow + 4 * C8);
  short8 vfa[4], vfb[4];
#pragma unroll
  for (int ct = 0; ct < 4; ++ct) vfa[ct] = *(const short8*)(vrow[ct]);

  for (int jb = 0; jb < NN; jb += 64) {
    // ---------- half A: uses kf0/kf1 (rows jb+*), V=vfa (cols jb+*) ----------
    {
      const int j1 = jb + 32;
      // prefetch V and K for half B
#pragma unroll
      for (int ct = 0; ct < 4; ++ct)
        vfb[ct] = *(const short8*)(vrow[ct] + j1);
      short8 kf0n = *(const short8*)(krow + (size_t)j1 * C8);
      short8 kf1n = *(const short8*)(krow + (size_t)j1 * C8 + 4 * C8);
      floatx4 s1a[4], s2a[4];
#pragma unroll
      for (int it = 0; it < 4; ++it) {
        s1a[it] = __builtin_amdgcn_mfma_f32_16x16x32_bf16(kf0, qf[it], zf, 0, 0, 0);
        s2a[it] = __builtin_amdgcn_mfma_f32_16x16x32_bf16(kf1, qf[it], zf, 0, 0, 0);
      }
#pragma unroll
      for (int it = 0; it < 4; ++it) {
        union { uintx4 pw; short8 pf; } pp;
        pp.pw[0] = cvt_pk_bf16(fast_exp2(s1a[it][0]), fast_exp2(s1a[it][1]));
        pp.pw[1] = cvt_pk_bf16(fast_exp2(s1a[it][2]), fast_exp2(s1a[it][3]));
        pp.pw[2] = cvt_pk_bf16(fast_exp2(s2a[it][0]), fast_exp2(s2a[it][1]));
        pp.pw[3] = cvt_pk_bf16(fast_exp2(s2a[it][2]), fast_exp2(s2a[it][3]));
        short8 pfi = pp.pf;
        rsacc[it] = __builtin_amdgcn_mfma_f32_16x16x32_bf16(ones, pfi, rsacc[it], 0, 0, 0);
#pragma unroll
        for (int ct = 0; ct < 4; ++ct)
          acc[ct][it] = __builtin_amdgcn_mfma_f32_16x16x32_bf16(
              vfa[ct], pfi, acc[ct][it], 0, 0, 0);
      }
      kf0 = kf0n;
      kf1 = kf1n;
    }
    // ---------- half B: uses kf0/kf1 (rows jb+32+*), V=vfb ----------
    {
      const int j2 = (jb + 64) & (NN - 1);  // wrap harmless
      // prefetch V and K for next iteration's half A
#pragma unroll
      for (int ct = 0; ct < 4; ++ct)
        vfa[ct] = *(const short8*)(vrow[ct] + j2);
      short8 kf0n = *(const short8*)(krow + (size_t)j2 * C8);
      short8 kf1n = *(const short8*)(krow + (size_t)j2 * C8 + 4 * C8);
      floatx4 s1a[4], s2a[4];
#pragma unroll
      for (int it = 0; it < 4; ++it) {
        s1a[it] = __builtin_amdgcn_mfma_f32_16x16x32_bf16(kf0, qf[it], zf, 0, 0, 0);
        s2a[it] = __builtin_amdgcn_mfma_f32_16x16x32_bf16(kf1, qf[it], zf, 0, 0, 0);
      }
#pragma unroll
      for (int it = 0; it < 4; ++it) {
        union { uintx4 pw; short8 pf; } pp;
        pp.pw[0] = cvt_pk_bf16(fast_exp2(s1a[it][0]), fast_exp2(s1a[it][1]));
        pp.pw[1] = cvt_pk_bf16(fast_exp2(s1a[it][2]), fast_exp2(s1a[it][3]));
        pp.pw[2] = cvt_pk_bf16(fast_exp2(s2a[it][0]), fast_exp2(s2a[it][1]));
        pp.pw[3] = cvt_pk_bf16(fast_exp2(s2a[it][2]), fast_exp2(s2a[it][3]));
        short8 pfi = pp.pf;
        rsacc[it] = __builtin_amdgcn_mfma_f32_16x16x32_bf16(ones, pfi, rsacc[it], 0, 0, 0);
#pragma unroll
        for (int ct = 0; ct < 4; ++ct)
          acc[ct][it] = __builtin_amdgcn_mfma_f32_16x16x32_bf16(
              vfb[ct], pfi, acc[ct][it], 0, 0, 0);
      }
      kf0 = kf0n;
      kf1 = kf1n;
    }
  }
  // ones-MFMA gave every lane the full denominator for its i-col (li):
  // C[row, li] = sum_k P[k, li], accumulated over all j-blocks.
  float inv[4];
#pragma unroll
  for (int it = 0; it < 4; ++it) inv[it] = 1.0f / rsacc[it][0];
  float* ob = outs_s + (size_t)g * CC * NN + i0;
#pragma unroll
  for (int ct = 0; ct < 4; ++ct)
#pragma unroll
    for (int it = 0; it < 4; ++it)
#pragma unroll
      for (int r = 0; r < 4; ++r) {
        int c = c0 + ct * 16 + q * 4 + r;
        ob[(size_t)c * NN + it * 16 + li] = acc[ct][it][r] * inv[it];
      }
}

// ---------------------------------------------------------------------------
// G3: final projection with T2 fused (3-way s-sum + gamma + transpose staged
// through LDS), n-tile 32, grid (128, 4).
// ---------------------------------------------------------------------------
__global__ void __launch_bounds__(256) final_kernel(
    const float* __restrict__ outs_s, const __hip_bfloat16* __restrict__ xfT,
    const __hip_bfloat16* __restrict__ WfB, const float* __restrict__ bfv,
    const float* __restrict__ gp, float* __restrict__ out) {
  __shared__ float ts[64][33];
  __shared__ __hip_bfloat16 Pn[32][280];
  const int b = blockIdx.y, n0 = blockIdx.x * 32;
  const int t = threadIdx.x, w = t >> 6, lane = t & 63;
  const int q = lane >> 4, li = lane & 15;
  const float sc = gp[0];
  for (int cc = 0; cc < 4; ++cc) {
    const int c0 = cc * 64;
    const float* X0 = outs_s + ((size_t)(0 + b) * CC + c0) * NN + n0;
    const float* X1 = outs_s + ((size_t)(4 + b) * CC + c0) * NN + n0;
    const float* X2 = outs_s + ((size_t)(8 + b) * CC + c0) * NN + n0;
    for (int idx = t; idx < 64 * 32; idx += 256) {
      int r = idx >> 5, col = idx & 31;
      size_t off = (size_t)r * NN + col;
      ts[r][col] = X0[off] + X1[off] + X2[off];
    }
    __syncthreads();
    for (int idx = t; idx < 32 * 32; idx += 256) {
      int n = idx >> 5, pc = idx & 31;
      ((unsigned*)&Pn[n][c0])[pc] =
          pack_bf16(ts[2 * pc][n] * sc, ts[2 * pc + 1][n] * sc);
    }
    __syncthreads();
  }
  const __hip_bfloat16* xT = xfT + (size_t)b * NN * CC;
  const int o_w = w * 64;
  floatx4 acc[4][2];
  floatx4 zf = {0.f, 0.f, 0.f, 0.f};
#pragma unroll
  for (int ot = 0; ot < 4; ++ot)
#pragma unroll
    for (int nt = 0; nt < 2; ++nt) acc[ot][nt] = zf;
#pragma unroll
  for (int kc = 0; kc < 16; ++kc) {
    short8 a[4], bfr[2];
#pragma unroll
    for (int ot = 0; ot < 4; ++ot)
      a[ot] = *(const short8*)(WfB + (size_t)(o_w + ot * 16 + li) * (2 * CC) +
                               kc * 32 + q * 8);
    if (kc < 8) {
#pragma unroll
      for (int nt = 0; nt < 2; ++nt)
        bfr[nt] = *(const short8*)(&Pn[nt * 16 + li][kc * 32 + q * 8]);
    } else {
#pragma unroll
      for (int nt = 0; nt < 2; ++nt)
        bfr[nt] = *(const short8*)(xT + (size_t)(n0 + nt * 16 + li) * CC +
                                   (kc - 8) * 32 + q * 8);
    }
#pragma unroll
    for (int ot = 0; ot < 4; ++ot)
#pragma unroll
      for (int nt = 0; nt < 2; ++nt)
        acc[ot][nt] = __builtin_amdgcn_mfma_f32_16x16x32_bf16(a[ot], bfr[nt],
                                                              acc[ot][nt], 0, 0, 0);
  }
  float* ob = out + (size_t)b * CC * NN;
#pragma unroll
  for (int ot = 0; ot < 4; ++ot)
#pragma unroll
    for (int r = 0; r < 4; ++r) {
      int o = o_w + ot * 16 + q * 4 + r;
      float bo = bfv[o];
#pragma unroll
      for (int nt = 0; nt < 2; ++nt)
        ob[(size_t)o * NN + n0 + nt * 16 + li] = acc[ot][nt][r] + bo;
    }
}

// ---------------------------------------------------------------------------
extern "C" void kernel_launch(void* const* d_in, const int* in_sizes, int n_in,
                              void* d_out, int out_size, void* d_ws,
                              size_t ws_size, hipStream_t stream) {
  const float* x_f = (const float*)d_in[0];
  const float* x_b = (const float*)d_in[1];
  const float* Wq  = (const float*)d_in[2];
  const float* bq  = (const float*)d_in[3];
  const float* Wk  = (const float*)d_in[4];
  const float* bk  = (const float*)d_in[5];
  const float* Wv  = (const float*)d_in[6];
  const float* bv  = (const float*)d_in[7];
  const float* Wf  = (const float*)d_in[8];
  const float* bf  = (const float*)d_in[9];
  const float* gm  = (const float*)d_in[10];
  float* out = (float*)d_out;

  // workspace layout — peak 84.4 MB via aliasing:
  //   [ 0..24) vB       bf16 [12][256][4096]   (projqkv -> attn)
  //   [24..32) xfT      bf16 [4][4096][256]    (transpose -> final)
  //   [32..80) outs_s   f32  [12][256][4096]   (attn -> final)
  //            xbT      bf16 [12][4096][256]   (transpose -> projqkv) ALIAS
  //   [80..83) qT, [83..84) kT, [84..84.41) weights
  char* ws = (char*)d_ws;
  __hip_bfloat16* vB     = (__hip_bfloat16*)ws;                         // 24 MB
  __hip_bfloat16* xfT    = (__hip_bfloat16*)(ws + ((size_t)24 << 20));  //  8 MB
  float*          outs_s = (float*)(ws + ((size_t)32 << 20));           // 48 MB
  __hip_bfloat16* xbT    = (__hip_bfloat16*)(ws + ((size_t)32 << 20));  // 24 MB (alias outs_s)
  __hip_bfloat16* qT     = (__hip_bfloat16*)(ws + ((size_t)80 << 20));  //  3 MB
  __hip_bfloat16* kT     = (__hip_bfloat16*)(ws + ((size_t)83 << 20));  //  1 MB
  __hip_bfloat16* WqB    = (__hip_bfloat16*)(ws + ((size_t)84 << 20));  // 16 KB
  __hip_bfloat16* WkB    = WqB + 8192;                                  // 16 KB
  __hip_bfloat16* WvB    = WkB + 8192;                                  // 128 KB
  __hip_bfloat16* WfB    = WvB + 65536;                                 // 256 KB

  hipLaunchKernelGGL(transpose_in_kernel, dim3(NN / 64, CC / 64, 17),
                     dim3(256), 0, stream, x_b, x_f, xbT, xfT,
                     Wq, Wk, Wv, Wf, WqB, WkB, WvB, WfB);
  hipLaunchKernelGGL(projqkv_kernel, dim3(NN / 64, 28), dim3(256), 0, stream,
                     xbT, xfT, WqB, WkB, WvB, bq, bk, bv, qT, kT, vB);
  hipLaunchKernelGGL(attn_kernel, dim3(768), dim3(256), 0, stream,
                     qT, kT, vB, outs_s);
  hipLaunchKernelGGL(final_kernel, dim3(NN / 32, BB), dim3(256), 0, stream,
                     outs_s, xfT, WfB, bf, gm, out);
}

// Round 9
// 382.669 us; speedup vs baseline: 1.1606x; 1.1487x over previous
//
#include <hip/hip_runtime.h>
#include <hip/hip_bf16.h>

#define BB 4
#define CC 256
#define NN 4096
#define SS 3
#define C8 32
#define L2E 1.4426950408889634f

typedef __attribute__((ext_vector_type(8))) short short8;
typedef __attribute__((ext_vector_type(4))) float floatx4;

static __device__ inline unsigned pack_bf16(float a, float b) {
  union { __hip_bfloat16 h; unsigned short u; } ua, ub;
  ua.h = __float2bfloat16(a);
  ub.h = __float2bfloat16(b);
  return ((unsigned)ub.u << 16) | (unsigned)ua.u;
}

// hardware packed convert: one v_cvt_pk_bf16_f32 (RNE) per pair
static __device__ inline unsigned cvt_pk_bf16(float a, float b) {
  union { __hip_bfloat162 h2; unsigned u; } cv;
  cv.h2 = __float22bfloat162_rn(make_float2(a, b));
  return cv.u;
}

static __device__ inline float fast_exp2(float x) {
#if __has_builtin(__builtin_amdgcn_exp2f)
  return __builtin_amdgcn_exp2f(x);
#else
  return exp2f(x);
#endif
}

// ---------------------------------------------------------------------------
// T1: input transposes + weight convert, merged.
// z<12: xbT[z] <- x_b[z]; z<16: xfT[z-12] <- x_f; z==16: weight fp32->bf16.
// ---------------------------------------------------------------------------
__global__ void __launch_bounds__(256) transpose_in_kernel(
    const float* __restrict__ xb, const float* __restrict__ xf,
    __hip_bfloat16* __restrict__ xbT, __hip_bfloat16* __restrict__ xfT,
    const float* __restrict__ Wq, const float* __restrict__ Wk,
    const float* __restrict__ Wv, const float* __restrict__ Wf,
    __hip_bfloat16* __restrict__ WqB, __hip_bfloat16* __restrict__ WkB,
    __hip_bfloat16* __restrict__ WvB, __hip_bfloat16* __restrict__ WfB) {
  __shared__ float ts[64][65];
  const int z = blockIdx.z;
  const int t = threadIdx.x;
  if (z == 16) {  // weight conversion plane: 256 blocks x 256 thr, 4 strides
    for (int idx = (blockIdx.y * 64 + blockIdx.x) * 256 + t; idx < 212992;
         idx += 65536) {
      if (idx < 8192) WqB[idx] = __float2bfloat16(Wq[idx] * L2E);
      else if (idx < 16384) WkB[idx - 8192] = __float2bfloat16(Wk[idx - 8192]);
      else if (idx < 81920) WvB[idx - 16384] = __float2bfloat16(Wv[idx - 16384]);
      else WfB[idx - 81920] = __float2bfloat16(Wf[idx - 81920]);
    }
    return;
  }
  const bool isb = (z < 12);
  const int g = isb ? z : z - 12;
  const float* X = (isb ? xb : xf) + (size_t)g * CC * NN;
  __hip_bfloat16* out = (isb ? xbT : xfT) + (size_t)g * NN * CC;
  const int c0 = blockIdx.y * 64, n0 = blockIdx.x * 64;
  const float* Xg = X + (size_t)c0 * NN + n0;
  for (int idx = t; idx < 64 * 64; idx += 256) {
    int r = idx >> 6, qq = idx & 63;
    ts[r][qq] = Xg[(size_t)r * NN + qq];
  }
  __syncthreads();
  __hip_bfloat16* og = out + (size_t)n0 * CC + c0;
  for (int idx = t; idx < 64 * 32; idx += 256) {
    int n = idx >> 5, pc = idx & 31;
    ((unsigned*)(og + (size_t)n * CC))[pc] = pack_bf16(ts[2 * pc][n], ts[2 * pc + 1][n]);
  }
}

// ---------------------------------------------------------------------------
// G1+G2 merged: y<12 -> v projection for g=y; y>=12 -> q/k projection.
// ---------------------------------------------------------------------------
__global__ void __launch_bounds__(256) projqkv_kernel(
    const __hip_bfloat16* __restrict__ xbT, const __hip_bfloat16* __restrict__ xfT,
    const __hip_bfloat16* __restrict__ WqB, const __hip_bfloat16* __restrict__ WkB,
    const __hip_bfloat16* __restrict__ WvB,
    const float* __restrict__ bq, const float* __restrict__ bk,
    const float* __restrict__ bv,
    __hip_bfloat16* __restrict__ qT, __hip_bfloat16* __restrict__ kT,
    __hip_bfloat16* __restrict__ vB) {
  const int y = blockIdx.y;
  const int t = threadIdx.x, w = t >> 6, lane = t & 63;
  const int q = lane >> 4, li = lane & 15;
  floatx4 zf = {0.f, 0.f, 0.f, 0.f};
  if (y < 12) {  // ---- v projection: vB[g][o][n] = Wv @ xbT[g] + bv ----
    const int g = y, n0 = blockIdx.x * 64;
    const __hip_bfloat16* src = xbT + (size_t)g * NN * CC;
    __hip_bfloat16* dst = vB + (size_t)g * CC * NN;
    const int o_w = w * 64;
    floatx4 acc[4][4];
#pragma unroll
    for (int ot = 0; ot < 4; ++ot)
#pragma unroll
      for (int nt = 0; nt < 4; ++nt) acc[ot][nt] = zf;
#pragma unroll
    for (int kc = 0; kc < 8; ++kc) {
      short8 a[4], bfr[4];
#pragma unroll
      for (int ot = 0; ot < 4; ++ot)
        a[ot] = *(const short8*)(WvB + (size_t)(o_w + ot * 16 + li) * CC + kc * 32 + q * 8);
#pragma unroll
      for (int nt = 0; nt < 4; ++nt)
        bfr[nt] = *(const short8*)(src + (size_t)(n0 + nt * 16 + li) * CC + kc * 32 + q * 8);
#pragma unroll
      for (int ot = 0; ot < 4; ++ot)
#pragma unroll
        for (int nt = 0; nt < 4; ++nt)
          acc[ot][nt] = __builtin_amdgcn_mfma_f32_16x16x32_bf16(a[ot], bfr[nt],
                                                                acc[ot][nt], 0, 0, 0);
    }
#pragma unroll
    for (int ot = 0; ot < 4; ++ot) {
#pragma unroll
      for (int r = 0; r < 4; ++r) {
        int o = o_w + ot * 16 + q * 4 + r;
        float bo = bv[o];
#pragma unroll
        for (int nt = 0; nt < 4; ++nt)
          dst[(size_t)o * NN + n0 + nt * 16 + li] =
              __float2bfloat16(acc[ot][nt][r] + bo);
      }
    }
  } else {  // ---- q/k projection, n-tile 64 (16/wave) ----
    const int gg = y - 12;
    const bool qm = (gg < 12);
    const int g = qm ? gg : gg - 12;
    const __hip_bfloat16* src = (qm ? xbT : xfT) + (size_t)g * NN * CC;
    const __hip_bfloat16* W = qm ? WqB : WkB;
    const float* bias = qm ? bq : bk;
    const float bscale = qm ? L2E : 1.f;
    __hip_bfloat16* dst = (qm ? qT : kT) + (size_t)g * NN * C8;
    const int n_w = blockIdx.x * 64 + w * 16;
    floatx4 acc[2];
    acc[0] = zf; acc[1] = zf;
#pragma unroll
    for (int kc = 0; kc < 8; ++kc) {
      short8 a[2];
#pragma unroll
      for (int ot = 0; ot < 2; ++ot)
        a[ot] = *(const short8*)(W + (size_t)(ot * 16 + li) * CC + kc * 32 + q * 8);
      short8 bfr = *(const short8*)(src + (size_t)(n_w + li) * CC + kc * 32 + q * 8);
#pragma unroll
      for (int ot = 0; ot < 2; ++ot)
        acc[ot] = __builtin_amdgcn_mfma_f32_16x16x32_bf16(a[ot], bfr, acc[ot], 0, 0, 0);
    }
#pragma unroll
    for (int ot = 0; ot < 2; ++ot) {
      float bv0 = bias[ot * 16 + q * 4 + 0] * bscale;
      float bv1 = bias[ot * 16 + q * 4 + 1] * bscale;
      float bv2 = bias[ot * 16 + q * 4 + 2] * bscale;
      float bv3 = bias[ot * 16 + q * 4 + 3] * bscale;
      int n = n_w + li;
      uint2 pk;
      pk.x = pack_bf16(acc[ot][0] + bv0, acc[ot][1] + bv1);
      pk.y = pack_bf16(acc[ot][2] + bv2, acc[ot][3] + bv3);
      *(uint2*)(dst + (size_t)n * C8 + ot * 16 + q * 4) = pk;
    }
  }
}

// ---------------------------------------------------------------------------
// K3: MFMA flash attention — the PROVEN round-2 kernel (215us, 3 waves/SIMD,
// VGPR 104+64agpr): 128-j outer iter, 4x8KB P buffers, ONE __syncthreads per
// 128 j, setprio on PV, plain stores to per-s fp32 slabs. Barrier-free
// variants (rounds 6-8) plateaued at 285-290us — structure retired.
// Only change vs round 2: pack via v_cvt_pk_bf16_f32 (RNE, same numerics).
// ---------------------------------------------------------------------------
__global__ void __launch_bounds__(256) attn_kernel(
    const __hip_bfloat16* __restrict__ qT, const __hip_bfloat16* __restrict__ kT,
    const __hip_bfloat16* __restrict__ vB, float* __restrict__ outs_s) {
  __shared__ uint4 Ps4[4 * 64 * 8];  // 4 x 8KB P buffers, 16B-chunk XOR swizzle
  __shared__ float lsum[64];
  char* Ps0 = (char*)Ps4;
  const int x_ = blockIdx.x;
  const int wk = (x_ & 7) * 96 + (x_ >> 3);  // contiguous range per XCD
  const int g  = wk >> 6;                    // 0..11 (= s*4+b)
  const int i0 = (wk & 63) << 6;
  const int b  = g & 3;
  const int t  = threadIdx.x;
  const int w  = t >> 6;
  const int lane = t & 63, q = lane >> 4, li = lane & 15;

  if (t < 64) lsum[t] = 0.f;

  short8 qf[4];
#pragma unroll
  for (int it = 0; it < 4; ++it)
    qf[it] = *(const short8*)(qT + ((size_t)g * NN + i0 + it * 16 + li) * C8 + q * 8);

  floatx4 acc[4][4];
  floatx4 zf = {0.f, 0.f, 0.f, 0.f};
#pragma unroll
  for (int ct = 0; ct < 4; ++ct)
#pragma unroll
    for (int it = 0; it < 4; ++it) acc[ct][it] = zf;
  float rsum[4] = {0.f, 0.f, 0.f, 0.f};

  const __hip_bfloat16* kb = kT + (size_t)b * NN * C8;
  const __hip_bfloat16* vb = vB + (size_t)g * CC * NN;
  short8 kf0 = *(const short8*)(kb + (size_t)(0 + w * 16 + li) * C8 + q * 8);
  short8 kf1 = *(const short8*)(kb + (size_t)(64 + w * 16 + li) * C8 + q * 8);

  for (int j0 = 0; j0 < NN; j0 += 128) {
    int j0n = (j0 + 128) & (NN - 1);
    char* PsA = Ps0 + ((j0 >> 6) & 2) * 8192;  // pair {0,1} / {2,3} alternates
    char* PsB = PsA + 8192;
    // V frags for subtile A: issue first so L2 latency hides under S/exp work
    short8 vfA[4][2];
#pragma unroll
    for (int ct = 0; ct < 4; ++ct)
#pragma unroll
      for (int kk = 0; kk < 2; ++kk)
        vfA[ct][kk] = *(const short8*)(vb + (size_t)(w * 64 + ct * 16 + li) * NN +
                                       j0 + kk * 32 + q * 8);
    // --- subtile A: S^T strip, exp2, pack, LDS write (stA dies here) ---
    {
      floatx4 stA[4];
#pragma unroll
      for (int it = 0; it < 4; ++it)
        stA[it] = __builtin_amdgcn_mfma_f32_16x16x32_bf16(kf0, qf[it], zf, 0, 0, 0);
      kf0 = *(const short8*)(kb + (size_t)(j0n + w * 16 + li) * C8 + q * 8);
      uint2 pk[4];
#pragma unroll
      for (int it = 0; it < 4; ++it) {
        float e0 = fast_exp2(stA[it][0]), e1 = fast_exp2(stA[it][1]);
        float e2 = fast_exp2(stA[it][2]), e3 = fast_exp2(stA[it][3]);
        rsum[it] += (e0 + e1) + (e2 + e3);
        pk[it].x = cvt_pk_bf16(e0, e1);
        pk[it].y = cvt_pk_bf16(e2, e3);
      }
#pragma unroll
      for (int it = 0; it < 4; ++it) {
        int row = it * 16 + li;
        int chunk = (w * 2 + (q >> 1)) ^ (row & 7);
        *(uint2*)(PsA + row * 128 + chunk * 16 + (q & 1) * 8) = pk[it];
      }
    }
    // --- subtile B: S^T strip, exp2, pack, LDS write ---
    {
      floatx4 stB[4];
#pragma unroll
      for (int it = 0; it < 4; ++it)
        stB[it] = __builtin_amdgcn_mfma_f32_16x16x32_bf16(kf1, qf[it], zf, 0, 0, 0);
      kf1 = *(const short8*)(kb + (size_t)(j0n + 64 + w * 16 + li) * C8 + q * 8);
      uint2 pk[4];
#pragma unroll
      for (int it = 0; it < 4; ++it) {
        float e0 = fast_exp2(stB[it][0]), e1 = fast_exp2(stB[it][1]);
        float e2 = fast_exp2(stB[it][2]), e3 = fast_exp2(stB[it][3]);
        rsum[it] += (e0 + e1) + (e2 + e3);
        pk[it].x = cvt_pk_bf16(e0, e1);
        pk[it].y = cvt_pk_bf16(e2, e3);
      }
#pragma unroll
      for (int it = 0; it < 4; ++it) {
        int row = it * 16 + li;
        int chunk = (w * 2 + (q >> 1)) ^ (row & 7);
        *(uint2*)(PsB + row * 128 + chunk * 16 + (q & 1) * 8) = pk[it];
      }
    }
    __syncthreads();  // one barrier per 128 j; alternating pairs make reads safe
    // --- PV subtile A (vfA dies here) ---
    __builtin_amdgcn_s_setprio(1);
#pragma unroll
    for (int kk = 0; kk < 2; ++kk) {
      short8 pf[4];
#pragma unroll
      for (int it = 0; it < 4; ++it) {
        int row = it * 16 + li;
        int chunk = (kk * 4 + q) ^ (row & 7);
        pf[it] = *(const short8*)(PsA + row * 128 + chunk * 16);
      }
#pragma unroll
      for (int ct = 0; ct < 4; ++ct)
#pragma unroll
        for (int it = 0; it < 4; ++it)
          acc[ct][it] = __builtin_amdgcn_mfma_f32_16x16x32_bf16(
              vfA[ct][kk], pf[it], acc[ct][it], 0, 0, 0);
    }
    __builtin_amdgcn_s_setprio(0);
    // V frags for subtile B (vfA dead -> regs reuse)
    short8 vfB[4][2];
#pragma unroll
    for (int ct = 0; ct < 4; ++ct)
#pragma unroll
      for (int kk = 0; kk < 2; ++kk)
        vfB[ct][kk] = *(const short8*)(vb + (size_t)(w * 64 + ct * 16 + li) * NN +
                                       j0 + 64 + kk * 32 + q * 8);
    // --- PV subtile B ---
    __builtin_amdgcn_s_setprio(1);
#pragma unroll
    for (int kk = 0; kk < 2; ++kk) {
      short8 pf[4];
#pragma unroll
      for (int it = 0; it < 4; ++it) {
        int row = it * 16 + li;
        int chunk = (kk * 4 + q) ^ (row & 7);
        pf[it] = *(const short8*)(PsB + row * 128 + chunk * 16);
      }
#pragma unroll
      for (int ct = 0; ct < 4; ++ct)
#pragma unroll
        for (int it = 0; it < 4; ++it)
          acc[ct][it] = __builtin_amdgcn_mfma_f32_16x16x32_bf16(
              vfB[ct][kk], pf[it], acc[ct][it], 0, 0, 0);
    }
    __builtin_amdgcn_s_setprio(0);
  }
#pragma unroll
  for (int it = 0; it < 4; ++it) {
    float v = rsum[it];
    v += __shfl_xor(v, 16, 64);
    v += __shfl_xor(v, 32, 64);
    if (lane < 16) atomicAdd(&lsum[it * 16 + li], v);
  }
  __syncthreads();
  float inv[4];
#pragma unroll
  for (int it = 0; it < 4; ++it) inv[it] = 1.0f / lsum[it * 16 + li];
  float* ob = outs_s + (size_t)g * CC * NN + i0;
#pragma unroll
  for (int ct = 0; ct < 4; ++ct)
#pragma unroll
    for (int it = 0; it < 4; ++it)
#pragma unroll
      for (int r = 0; r < 4; ++r) {
        int c = w * 64 + ct * 16 + q * 4 + r;
        ob[(size_t)c * NN + it * 16 + li] = acc[ct][it][r] * inv[it];
      }
}

// ---------------------------------------------------------------------------
// G3: final projection with T2 fused (3-way s-sum + gamma + transpose staged
// through LDS), n-tile 32, grid (128, 4).
// ---------------------------------------------------------------------------
__global__ void __launch_bounds__(256) final_kernel(
    const float* __restrict__ outs_s, const __hip_bfloat16* __restrict__ xfT,
    const __hip_bfloat16* __restrict__ WfB, const float* __restrict__ bfv,
    const float* __restrict__ gp, float* __restrict__ out) {
  __shared__ float ts[64][33];
  __shared__ __hip_bfloat16 Pn[32][280];
  const int b = blockIdx.y, n0 = blockIdx.x * 32;
  const int t = threadIdx.x, w = t >> 6, lane = t & 63;
  const int q = lane >> 4, li = lane & 15;
  const float sc = gp[0];
  for (int cc = 0; cc < 4; ++cc) {
    const int c0 = cc * 64;
    const float* X0 = outs_s + ((size_t)(0 + b) * CC + c0) * NN + n0;
    const float* X1 = outs_s + ((size_t)(4 + b) * CC + c0) * NN + n0;
    const float* X2 = outs_s + ((size_t)(8 + b) * CC + c0) * NN + n0;
    for (int idx = t; idx < 64 * 32; idx += 256) {
      int r = idx >> 5, col = idx & 31;
      size_t off = (size_t)r * NN + col;
      ts[r][col] = X0[off] + X1[off] + X2[off];
    }
    __syncthreads();
    for (int idx = t; idx < 32 * 32; idx += 256) {
      int n = idx >> 5, pc = idx & 31;
      ((unsigned*)&Pn[n][c0])[pc] =
          pack_bf16(ts[2 * pc][n] * sc, ts[2 * pc + 1][n] * sc);
    }
    __syncthreads();
  }
  const __hip_bfloat16* xT = xfT + (size_t)b * NN * CC;
  const int o_w = w * 64;
  floatx4 acc[4][2];
  floatx4 zf = {0.f, 0.f, 0.f, 0.f};
#pragma unroll
  for (int ot = 0; ot < 4; ++ot)
#pragma unroll
    for (int nt = 0; nt < 2; ++nt) acc[ot][nt] = zf;
#pragma unroll
  for (int kc = 0; kc < 16; ++kc) {
    short8 a[4], bfr[2];
#pragma unroll
    for (int ot = 0; ot < 4; ++ot)
      a[ot] = *(const short8*)(WfB + (size_t)(o_w + ot * 16 + li) * (2 * CC) +
                               kc * 32 + q * 8);
    if (kc < 8) {
#pragma unroll
      for (int nt = 0; nt < 2; ++nt)
        bfr[nt] = *(const short8*)(&Pn[nt * 16 + li][kc * 32 + q * 8]);
    } else {
#pragma unroll
      for (int nt = 0; nt < 2; ++nt)
        bfr[nt] = *(const short8*)(xT + (size_t)(n0 + nt * 16 + li) * CC +
                                   (kc - 8) * 32 + q * 8);
    }
#pragma unroll
    for (int ot = 0; ot < 4; ++ot)
#pragma unroll
      for (int nt = 0; nt < 2; ++nt)
        acc[ot][nt] = __builtin_amdgcn_mfma_f32_16x16x32_bf16(a[ot], bfr[nt],
                                                              acc[ot][nt], 0, 0, 0);
  }
  float* ob = out + (size_t)b * CC * NN;
#pragma unroll
  for (int ot = 0; ot < 4; ++ot)
#pragma unroll
    for (int r = 0; r < 4; ++r) {
      int o = o_w + ot * 16 + q * 4 + r;
      float bo = bfv[o];
#pragma unroll
      for (int nt = 0; nt < 2; ++nt)
        ob[(size_t)o * NN + n0 + nt * 16 + li] = acc[ot][nt][r] + bo;
    }
}

// ---------------------------------------------------------------------------
extern "C" void kernel_launch(void* const* d_in, const int* in_sizes, int n_in,
                              void* d_out, int out_size, void* d_ws,
                              size_t ws_size, hipStream_t stream) {
  const float* x_f = (const float*)d_in[0];
  const float* x_b = (const float*)d_in[1];
  const float* Wq  = (const float*)d_in[2];
  const float* bq  = (const float*)d_in[3];
  const float* Wk  = (const float*)d_in[4];
  const float* bk  = (const float*)d_in[5];
  const float* Wv  = (const float*)d_in[6];
  const float* bv  = (const float*)d_in[7];
  const float* Wf  = (const float*)d_in[8];
  const float* bf  = (const float*)d_in[9];
  const float* gm  = (const float*)d_in[10];
  float* out = (float*)d_out;

  // workspace layout — peak 84.4 MB via aliasing:
  //   [ 0..24) vB       bf16 [12][256][4096]   (projqkv -> attn)
  //   [24..32) xfT      bf16 [4][4096][256]    (transpose -> final)
  //   [32..80) outs_s   f32  [12][256][4096]   (attn -> final)
  //            xbT      bf16 [12][4096][256]   (transpose -> projqkv) ALIAS
  //   [80..83) qT, [83..84) kT, [84..84.41) weights
  char* ws = (char*)d_ws;
  __hip_bfloat16* vB     = (__hip_bfloat16*)ws;                         // 24 MB
  __hip_bfloat16* xfT    = (__hip_bfloat16*)(ws + ((size_t)24 << 20));  //  8 MB
  float*          outs_s = (float*)(ws + ((size_t)32 << 20));           // 48 MB
  __hip_bfloat16* xbT    = (__hip_bfloat16*)(ws + ((size_t)32 << 20));  // 24 MB (alias outs_s)
  __hip_bfloat16* qT     = (__hip_bfloat16*)(ws + ((size_t)80 << 20));  //  3 MB
  __hip_bfloat16* kT     = (__hip_bfloat16*)(ws + ((size_t)83 << 20));  //  1 MB
  __hip_bfloat16* WqB    = (__hip_bfloat16*)(ws + ((size_t)84 << 20));  // 16 KB
  __hip_bfloat16* WkB    = WqB + 8192;                                  // 16 KB
  __hip_bfloat16* WvB    = WkB + 8192;                                  // 128 KB
  __hip_bfloat16* WfB    = WvB + 65536;                                 // 256 KB

  hipLaunchKernelGGL(transpose_in_kernel, dim3(NN / 64, CC / 64, 17),
                     dim3(256), 0, stream, x_b, x_f, xbT, xfT,
                     Wq, Wk, Wv, Wf, WqB, WkB, WvB, WfB);
  hipLaunchKernelGGL(projqkv_kernel, dim3(NN / 64, 28), dim3(256), 0, stream,
                     xbT, xfT, WqB, WkB, WvB, bq, bk, bv, qT, kT, vB);
  hipLaunchKernelGGL(attn_kernel, dim3(768), dim3(256), 0, stream,
                     qT, kT, vB, outs_s);
  hipLaunchKernelGGL(final_kernel, dim3(NN / 32, BB), dim3(256), 0, stream,
                     outs_s, xfT, WfB, bf, gm, out);
}